// Round 6
// baseline (165.654 us; speedup 1.0000x reference)
//
#include <hip/hip_runtime.h>

// IoU assigner: N anchors x M gts (3D, 6 coords). Outputs (concatenated, f32):
//   out[0:N]   labels (-1 ignore, 0 neg, gt_label pos)
//   out[N:7N]  assigned boxes (gt box if pos, else -1.0)
//
// Bit-exact vs numpy f32: __f*_rn intrinsics (no FMA contraction), op order
// mirrors the jnp reference; argmax ties: first index (strict > scan).
//
// Structure (round 6): 2 anchors per thread. Rounds 3-5 (4 anchors, ~60-reg
// live set) hit a codegen pathology: allocator spilled anchor coords and
// reloaded them every g-iteration (~2700 cyc/iter). 2 anchors keeps the live
// set ~40 regs (round-1-like codegen, which ran clean at VGPR=20) while
// halving the per-thread LDS broadcast traffic vs 1 anchor/thread.
// Per-gt column max: LDS u64 slot atomicMax (round-1-proven), gated
// iou>=0.3, flushed once per block to global slots. Low-quality override
// fused into the last-finished block via ticket counter.
//
// ws layout: [0,1024) slots[128] u64; [1024,1028) ticket counter.

#define MMAX 128

template <int MC>
__global__ __launch_bounds__(256, 2) void iou_main(
    const float* __restrict__ bx, const float* __restrict__ gt,
    const int* __restrict__ gl,
    float* __restrict__ out_lab, float* __restrict__ out_bb,
    unsigned long long* __restrict__ slots, unsigned int* __restrict__ counter,
    int N, int Mrt, int nblocks)
{
    const int M = MC ? MC : Mrt;
    const int tid = threadIdx.x;

    // ---- stage gt boxes + area + label into LDS; zero LDS slots ----
    __shared__ float gb[MMAX][8];              // x0,y0,z0,x1 | y1,z1,area,label
    __shared__ unsigned long long lsl[MMAX];   // per-block per-gt max slot
    if (tid < M) {
        const float* gp = gt + (size_t)tid * 6;
        float x0 = gp[0], y0 = gp[1], z0 = gp[2];
        float x1 = gp[3], y1 = gp[4], z1 = gp[5];
        float area = __fmul_rn(__fmul_rn(__fsub_rn(x1, x0), __fsub_rn(y1, y0)),
                               __fsub_rn(z1, z0));
        gb[tid][0] = x0; gb[tid][1] = y0; gb[tid][2] = z0; gb[tid][3] = x1;
        gb[tid][4] = y1; gb[tid][5] = z1; gb[tid][6] = area;
        gb[tid][7] = (float)gl[tid];
    }
    if (tid < MMAX) lsl[tid] = 0ULL;
    __syncthreads();

    // ---- load 2 contiguous anchors (48B contiguous per thread) ----
    const long long base = ((long long)blockIdx.x * 256 + tid) * 2;
    const bool v0 = (base + 0 < (long long)N);
    const bool v1 = (base + 1 < (long long)N);

    float ax0_0 = 0.f, ay0_0 = 0.f, az0_0 = 0.f, ax1_0 = 0.f, ay1_0 = 0.f, az1_0 = 0.f;
    float ax0_1 = 0.f, ay0_1 = 0.f, az0_1 = 0.f, ax1_1 = 0.f, ay1_1 = 0.f, az1_1 = 0.f;

    if (v1) {
        const float4* p = (const float4*)(bx + base * 6);
        float4 q0 = p[0], q1 = p[1], q2 = p[2];
        ax0_0 = q0.x; ay0_0 = q0.y; az0_0 = q0.z; ax1_0 = q0.w;
        ay1_0 = q1.x; az1_0 = q1.y;
        ax0_1 = q1.z; ay0_1 = q1.w; az0_1 = q2.x; ax1_1 = q2.y;
        ay1_1 = q2.z; az1_1 = q2.w;
    } else if (v0) {
        const float* p = bx + base * 6;
        ax0_0 = p[0]; ay0_0 = p[1]; az0_0 = p[2];
        ax1_0 = p[3]; ay1_0 = p[4]; az1_0 = p[5];
    }

    const float a1_0 = __fmul_rn(__fmul_rn(__fsub_rn(ax1_0, ax0_0),
                        __fsub_rn(ay1_0, ay0_0)), __fsub_rn(az1_0, az0_0));
    const float a1_1 = __fmul_rn(__fmul_rn(__fsub_rn(ax1_1, ax0_1),
                        __fsub_rn(ay1_1, ay0_1)), __fsub_rn(az1_1, az0_1));

    // best=0: iou==0 never strict-beats it (matches jnp.argmax first-index,
    // all-zero row -> argmax 0).
    float best_0 = 0.f, best_1 = 0.f;
    int   barg_0 = 0,   barg_1 = 0;

    for (int g = 0; g < M; ++g) {
        const float4 glo = *(const float4*)&gb[g][0];   // x0,y0,z0,x1 (broadcast)
        const float4 ghi = *(const float4*)&gb[g][4];   // y1,z1,area,label
        {
            float cx = fmaxf(__fsub_rn(fminf(ax1_0, glo.w), fmaxf(ax0_0, glo.x)), 0.f);
            float cy = fmaxf(__fsub_rn(fminf(ay1_0, ghi.x), fmaxf(ay0_0, glo.y)), 0.f);
            float cz = fmaxf(__fsub_rn(fminf(az1_0, ghi.y), fmaxf(az0_0, glo.z)), 0.f);
            float inter = __fmul_rn(__fmul_rn(cx, cy), cz);
            if (inter > 0.f) {                  // ~0.3% of pairs
                float den = __fadd_rn(__fsub_rn(__fadd_rn(a1_0, ghi.z), inter), 1e-7f);
                float iou = __fdiv_rn(inter, den);
                if (iou > best_0) { best_0 = iou; barg_0 = g; }
                if (iou >= 0.3f) {
                    // slot != 0 <=> column max >= MIN_POS_IOU; smallest-anchor
                    // tie-break via ~anchor in low bits.
                    unsigned long long enc =
                        ((unsigned long long)__float_as_uint(iou) << 32) |
                        (unsigned long long)(0xFFFFFFFFu - (unsigned)(base + 0));
                    atomicMax(&lsl[g], enc);
                }
            }
        }
        {
            float cx = fmaxf(__fsub_rn(fminf(ax1_1, glo.w), fmaxf(ax0_1, glo.x)), 0.f);
            float cy = fmaxf(__fsub_rn(fminf(ay1_1, ghi.x), fmaxf(ay0_1, glo.y)), 0.f);
            float cz = fmaxf(__fsub_rn(fminf(az1_1, ghi.y), fmaxf(az0_1, glo.z)), 0.f);
            float inter = __fmul_rn(__fmul_rn(cx, cy), cz);
            if (inter > 0.f) {
                float den = __fadd_rn(__fsub_rn(__fadd_rn(a1_1, ghi.z), inter), 1e-7f);
                float iou = __fdiv_rn(inter, den);
                if (iou > best_1) { best_1 = iou; barg_1 = g; }
                if (iou >= 0.3f) {
                    unsigned long long enc =
                        ((unsigned long long)__float_as_uint(iou) << 32) |
                        (unsigned long long)(0xFFFFFFFFu - (unsigned)(base + 1));
                    atomicMax(&lsl[g], enc);
                }
            }
        }
    }

    // ---- epilogue: labels + boxes ----
    const bool p0 = best_0 >= 0.7f, p1 = best_1 >= 0.7f;
    const float4 l0 = *(const float4*)&gb[barg_0][0], h0 = *(const float4*)&gb[barg_0][4];
    const float4 l1 = *(const float4*)&gb[barg_1][0], h1 = *(const float4*)&gb[barg_1][4];
    const float lab0 = p0 ? h0.w : (best_0 < 0.3f ? 0.f : -1.f);
    const float lab1 = p1 ? h1.w : (best_1 < 0.3f ? 0.f : -1.f);

    if (v1) {
        *(float2*)(out_lab + base) = make_float2(lab0, lab1);
        float4* ob = (float4*)(out_bb + base * 6);
        ob[0] = make_float4(p0 ? l0.x : -1.f, p0 ? l0.y : -1.f,
                            p0 ? l0.z : -1.f, p0 ? l0.w : -1.f);
        ob[1] = make_float4(p0 ? h0.x : -1.f, p0 ? h0.y : -1.f,
                            p1 ? l1.x : -1.f, p1 ? l1.y : -1.f);
        ob[2] = make_float4(p1 ? l1.z : -1.f, p1 ? l1.w : -1.f,
                            p1 ? h1.x : -1.f, p1 ? h1.y : -1.f);
    } else if (v0) {
        out_lab[base] = lab0;
        float* ob = out_bb + base * 6;
        ob[0] = p0 ? l0.x : -1.f; ob[1] = p0 ? l0.y : -1.f;
        ob[2] = p0 ? l0.z : -1.f; ob[3] = p0 ? l0.w : -1.f;
        ob[4] = p0 ? h0.x : -1.f; ob[5] = p0 ? h0.y : -1.f;
    }

    // ---- flush per-block per-gt maxima to global slots ----
    __syncthreads();
    for (int g = tid; g < M; g += 256) {
        unsigned long long v = lsl[g];
        if (v) atomicMax(&slots[g], v);
    }

    // ---- last-finished block applies the low-quality override ----
    __shared__ unsigned int s_ticket;
    __threadfence();                   // stores+atomics visible device-wide
    __syncthreads();
    if (tid == 0) s_ticket = atomicAdd(counter, 1u);
    __syncthreads();
    if (s_ticket != (unsigned)(nblocks - 1)) return;

    __shared__ int s_anchor[MMAX];
    __shared__ int s_cand[MMAX];
    int anchor = -1, cand = 0;
    if (tid < M) {
        unsigned long long v = atomicMax(&slots[tid], 0ULL);   // coherent read
        if (v != 0ULL) {               // gt_iou_max >= 0.3
            anchor = (int)(0xFFFFFFFFu - (unsigned)(v & 0xFFFFFFFFu));
            cand   = tid + 1;
        }
    }
    if (tid < MMAX) { s_anchor[tid] = anchor; s_cand[tid] = cand; }
    __syncthreads();
    if (tid < M && cand > 0) {
        // Largest gt index targeting the same anchor wins (.at[].max scatter).
        bool win = true;
        for (int j = 0; j < M; ++j)
            if (s_cand[j] > cand && s_anchor[j] == anchor) win = false;
        if (win) {
            out_lab[anchor] = gb[tid][7];
            float* ob = out_bb + (size_t)anchor * 6;
            ob[0] = gb[tid][0]; ob[1] = gb[tid][1]; ob[2] = gb[tid][2];
            ob[3] = gb[tid][3]; ob[4] = gb[tid][4]; ob[5] = gb[tid][5];
        }
    }
}

extern "C" void kernel_launch(void* const* d_in, const int* in_sizes, int n_in,
                              void* d_out, int out_size, void* d_ws, size_t ws_size,
                              hipStream_t stream)
{
    const float* bx = (const float*)d_in[0];
    const float* gt = (const float*)d_in[1];
    const int*   gl = (const int*)d_in[2];
    const int N = in_sizes[0] / 6;
    int M = in_sizes[1] / 6;
    if (M > MMAX) M = MMAX;

    float* out_lab = (float*)d_out;
    float* out_bb  = (float*)d_out + N;

    unsigned long long* slots = (unsigned long long*)d_ws;
    unsigned int* counter = (unsigned int*)((char*)d_ws + MMAX * 8);

    // counter + slots MUST be re-zeroed every call (ws is poisoned once, not
    // re-poisoned between timed replays).
    hipMemsetAsync(d_ws, 0, MMAX * 8 + 16, stream);

    const int threads_total = (N + 1) / 2;
    const int nblocks = (threads_total + 255) / 256;

    if (M == MMAX) {
        hipLaunchKernelGGL(iou_main<MMAX>, dim3(nblocks), dim3(256), 0, stream,
                           bx, gt, gl, out_lab, out_bb, slots, counter, N, M, nblocks);
    } else {
        hipLaunchKernelGGL(iou_main<0>, dim3(nblocks), dim3(256), 0, stream,
                           bx, gt, gl, out_lab, out_bb, slots, counter, N, M, nblocks);
    }
}

// Round 7
// 164.865 us; speedup vs baseline: 1.0048x; 1.0048x over previous
//
#include <hip/hip_runtime.h>

// IoU assigner: N anchors x M gts (3D, 6 coords). Outputs (concatenated, f32):
//   out[0:N]   labels (-1 ignore, 0 neg, gt_label pos)
//   out[N:7N]  assigned boxes (gt box if pos, else -1.0)
//
// Bit-exact vs numpy f32: __f*_rn intrinsics (no FMA contraction), op order
// mirrors the jnp reference; argmax ties: first index (strict > scan).
//
// Round-7 structure: 2 anchors/thread with a SINGLE-PATH, BRANCH-FREE anchor
// load. Rounds 3-6 all spilled the anchor coords to scratch (VGPR 20-44 for
// a 40-60 reg live set, WRITE_SIZE +8-10MB over the 14MB output = spill
// writes, 145-190us). Common feature was a multi-path load (if full {float4}
// else {scalar}) whose 12-24-value phi-merge hipcc demotes to scratch.
// Here: every thread loads 3x float4 from a CLAMPED always-valid address;
// validity and the odd-N shift are applied with pure ternaries (cndmask),
// so the loop's live-ins come from exactly one load site.
//
// gt tile in LDS as float4 pairs (2x ds_read_b128 per g). Per-gt column max:
// LDS u64 slot atomicMax gated iou>=0.3, flushed once per block; low-quality
// override fused into the last-finished block via ticket counter.
//
// ws layout: [0,1024) slots[128] u64; [1024,1028) ticket counter.

#define MMAX 128

template <int MC>
__global__ __launch_bounds__(256) void iou_main(
    const float* __restrict__ bx, const float* __restrict__ gt,
    const int* __restrict__ gl,
    float* __restrict__ out_lab, float* __restrict__ out_bb,
    unsigned long long* __restrict__ slots, unsigned int* __restrict__ counter,
    int N, int Mrt, int nblocks)
{
    const int M = MC ? MC : Mrt;
    const int tid = threadIdx.x;

    // ---- stage gt boxes + area + label into LDS; zero LDS slots ----
    __shared__ float4 gb4[MMAX * 2];   // [2g]={x0,y0,z0,x1}  [2g+1]={y1,z1,area,label}
    __shared__ unsigned long long lsl[MMAX];
    if (tid < M) {
        const float* gp = gt + (size_t)tid * 6;
        float x0 = gp[0], y0 = gp[1], z0 = gp[2];
        float x1 = gp[3], y1 = gp[4], z1 = gp[5];
        float area = __fmul_rn(__fmul_rn(__fsub_rn(x1, x0), __fsub_rn(y1, y0)),
                               __fsub_rn(z1, z0));
        gb4[2 * tid]     = make_float4(x0, y0, z0, x1);
        gb4[2 * tid + 1] = make_float4(y1, z1, area, (float)gl[tid]);
    }
    if (tid < MMAX) lsl[tid] = 0ULL;
    __syncthreads();

    // ---- branch-free load of 2 anchors from a clamped address ----
    const long long base  = ((long long)blockIdx.x * 256 + tid) * 2;
    long long sbase = base;
    if (sbase > (long long)N - 2) sbase = (long long)N - 2;  // always-valid window
    const bool valid0 = (base + 0 < (long long)N);
    const bool valid1 = (base + 1 < (long long)N);
    const bool shift  = valid0 && !valid1;   // odd-N tail: my anchor0 sits in slot 1

    const float4* p = (const float4*)(bx + sbase * 6);
    const float4 q0 = p[0], q1 = p[1], q2 = p[2];

    // anchor0 coords: slot0 normally, slot1 if shifted, zero box if invalid
    const float ax0_0 = valid0 ? (shift ? q1.z : q0.x) : 0.f;
    const float ay0_0 = valid0 ? (shift ? q1.w : q0.y) : 0.f;
    const float az0_0 = valid0 ? (shift ? q2.x : q0.z) : 0.f;
    const float ax1_0 = valid0 ? (shift ? q2.y : q0.w) : 0.f;
    const float ay1_0 = valid0 ? (shift ? q2.z : q1.x) : 0.f;
    const float az1_0 = valid0 ? (shift ? q2.w : q1.y) : 0.f;
    // anchor1 coords: slot1, zero box if invalid
    const float ax0_1 = valid1 ? q1.z : 0.f;
    const float ay0_1 = valid1 ? q1.w : 0.f;
    const float az0_1 = valid1 ? q2.x : 0.f;
    const float ax1_1 = valid1 ? q2.y : 0.f;
    const float ay1_1 = valid1 ? q2.z : 0.f;
    const float az1_1 = valid1 ? q2.w : 0.f;

    const float a1_0 = __fmul_rn(__fmul_rn(__fsub_rn(ax1_0, ax0_0),
                        __fsub_rn(ay1_0, ay0_0)), __fsub_rn(az1_0, az0_0));
    const float a1_1 = __fmul_rn(__fmul_rn(__fsub_rn(ax1_1, ax0_1),
                        __fsub_rn(ay1_1, ay0_1)), __fsub_rn(az1_1, az0_1));

    const unsigned enc0 = 0xFFFFFFFFu - (unsigned)(base + 0);  // loop-invariant
    const unsigned enc1 = 0xFFFFFFFFu - (unsigned)(base + 1);

    // best=0: iou==0 never strict-beats it (matches jnp.argmax first-index,
    // all-zero row -> argmax 0).
    float best_0 = 0.f, best_1 = 0.f;
    int   barg_0 = 0,   barg_1 = 0;

    for (int g = 0; g < M; ++g) {
        const float4 glo = gb4[2 * g];       // x0,y0,z0,x1 (broadcast b128)
        const float4 ghi = gb4[2 * g + 1];   // y1,z1,area,label
        {
            float cx = fmaxf(__fsub_rn(fminf(ax1_0, glo.w), fmaxf(ax0_0, glo.x)), 0.f);
            float cy = fmaxf(__fsub_rn(fminf(ay1_0, ghi.x), fmaxf(ay0_0, glo.y)), 0.f);
            float cz = fmaxf(__fsub_rn(fminf(az1_0, ghi.y), fmaxf(az0_0, glo.z)), 0.f);
            float inter = __fmul_rn(__fmul_rn(cx, cy), cz);
            if (inter > 0.f) {                  // ~0.3% of pairs
                float den = __fadd_rn(__fsub_rn(__fadd_rn(a1_0, ghi.z), inter), 1e-7f);
                float iou = __fdiv_rn(inter, den);
                if (iou > best_0) { best_0 = iou; barg_0 = g; }
                if (iou >= 0.3f) {
                    // slot != 0 <=> column max >= MIN_POS_IOU; smallest-anchor
                    // tie-break via ~anchor in low bits.
                    unsigned long long enc =
                        ((unsigned long long)__float_as_uint(iou) << 32) |
                        (unsigned long long)enc0;
                    atomicMax(&lsl[g], enc);
                }
            }
        }
        {
            float cx = fmaxf(__fsub_rn(fminf(ax1_1, glo.w), fmaxf(ax0_1, glo.x)), 0.f);
            float cy = fmaxf(__fsub_rn(fminf(ay1_1, ghi.x), fmaxf(ay0_1, glo.y)), 0.f);
            float cz = fmaxf(__fsub_rn(fminf(az1_1, ghi.y), fmaxf(az0_1, glo.z)), 0.f);
            float inter = __fmul_rn(__fmul_rn(cx, cy), cz);
            if (inter > 0.f) {
                float den = __fadd_rn(__fsub_rn(__fadd_rn(a1_1, ghi.z), inter), 1e-7f);
                float iou = __fdiv_rn(inter, den);
                if (iou > best_1) { best_1 = iou; barg_1 = g; }
                if (iou >= 0.3f) {
                    unsigned long long enc =
                        ((unsigned long long)__float_as_uint(iou) << 32) |
                        (unsigned long long)enc1;
                    atomicMax(&lsl[g], enc);
                }
            }
        }
    }

    // ---- epilogue: labels + boxes ----
    const bool p0 = best_0 >= 0.7f, p1 = best_1 >= 0.7f;
    const float4 l0 = gb4[2 * barg_0], h0 = gb4[2 * barg_0 + 1];
    const float4 l1 = gb4[2 * barg_1], h1 = gb4[2 * barg_1 + 1];
    const float lab0 = p0 ? h0.w : (best_0 < 0.3f ? 0.f : -1.f);
    const float lab1 = p1 ? h1.w : (best_1 < 0.3f ? 0.f : -1.f);

    if (valid1) {
        *(float2*)(out_lab + base) = make_float2(lab0, lab1);
        float4* ob = (float4*)(out_bb + base * 6);
        ob[0] = make_float4(p0 ? l0.x : -1.f, p0 ? l0.y : -1.f,
                            p0 ? l0.z : -1.f, p0 ? l0.w : -1.f);
        ob[1] = make_float4(p0 ? h0.x : -1.f, p0 ? h0.y : -1.f,
                            p1 ? l1.x : -1.f, p1 ? l1.y : -1.f);
        ob[2] = make_float4(p1 ? l1.z : -1.f, p1 ? l1.w : -1.f,
                            p1 ? h1.x : -1.f, p1 ? h1.y : -1.f);
    } else if (valid0) {
        out_lab[base] = lab0;
        float* ob = out_bb + base * 6;
        ob[0] = p0 ? l0.x : -1.f; ob[1] = p0 ? l0.y : -1.f;
        ob[2] = p0 ? l0.z : -1.f; ob[3] = p0 ? l0.w : -1.f;
        ob[4] = p0 ? h0.x : -1.f; ob[5] = p0 ? h0.y : -1.f;
    }

    // ---- flush per-block per-gt maxima to global slots ----
    __syncthreads();
    for (int g = tid; g < M; g += 256) {
        unsigned long long v = lsl[g];
        if (v) atomicMax(&slots[g], v);
    }

    // ---- last-finished block applies the low-quality override ----
    __shared__ unsigned int s_ticket;
    __threadfence();                   // flushes visible device-wide
    __syncthreads();
    if (tid == 0) s_ticket = atomicAdd(counter, 1u);
    __syncthreads();
    if (s_ticket != (unsigned)(nblocks - 1)) return;

    __shared__ int s_anchor[MMAX];
    __shared__ int s_cand[MMAX];
    int anchor = -1, cand = 0;
    if (tid < M) {
        unsigned long long v = atomicMax(&slots[tid], 0ULL);   // coherent read
        if (v != 0ULL) {               // gt_iou_max >= 0.3
            anchor = (int)(0xFFFFFFFFu - (unsigned)(v & 0xFFFFFFFFu));
            cand   = tid + 1;
        }
    }
    if (tid < MMAX) { s_anchor[tid] = anchor; s_cand[tid] = cand; }
    __syncthreads();
    if (tid < M && cand > 0) {
        // Largest gt index targeting the same anchor wins (.at[].max scatter).
        bool win = true;
        for (int j = 0; j < M; ++j)
            if (s_cand[j] > cand && s_anchor[j] == anchor) win = false;
        if (win) {
            const float4 gl4 = gb4[2 * tid], gh4 = gb4[2 * tid + 1];
            out_lab[anchor] = gh4.w;
            float* ob = out_bb + (size_t)anchor * 6;
            ob[0] = gl4.x; ob[1] = gl4.y; ob[2] = gl4.z;
            ob[3] = gl4.w; ob[4] = gh4.x; ob[5] = gh4.y;
        }
    }
}

extern "C" void kernel_launch(void* const* d_in, const int* in_sizes, int n_in,
                              void* d_out, int out_size, void* d_ws, size_t ws_size,
                              hipStream_t stream)
{
    const float* bx = (const float*)d_in[0];
    const float* gt = (const float*)d_in[1];
    const int*   gl = (const int*)d_in[2];
    const int N = in_sizes[0] / 6;
    int M = in_sizes[1] / 6;
    if (M > MMAX) M = MMAX;

    float* out_lab = (float*)d_out;
    float* out_bb  = (float*)d_out + N;

    unsigned long long* slots = (unsigned long long*)d_ws;
    unsigned int* counter = (unsigned int*)((char*)d_ws + MMAX * 8);

    // counter + slots MUST be re-zeroed every call (ws is poisoned once, not
    // re-poisoned between timed replays).
    hipMemsetAsync(d_ws, 0, MMAX * 8 + 16, stream);

    const int threads_total = (N + 1) / 2;
    const int nblocks = (threads_total + 255) / 256;

    if (M == MMAX) {
        hipLaunchKernelGGL(iou_main<MMAX>, dim3(nblocks), dim3(256), 0, stream,
                           bx, gt, gl, out_lab, out_bb, slots, counter, N, M, nblocks);
    } else {
        hipLaunchKernelGGL(iou_main<0>, dim3(nblocks), dim3(256), 0, stream,
                           bx, gt, gl, out_lab, out_bb, slots, counter, N, M, nblocks);
    }
}

// Round 8
// 163.166 us; speedup vs baseline: 1.0152x; 1.0104x over previous
//
#include <hip/hip_runtime.h>

// IoU assigner: N anchors x M gts (3D, 6 coords). Outputs (concatenated, f32):
//   out[0:N]   labels (-1 ignore, 0 neg, gt_label pos)
//   out[N:7N]  assigned boxes (gt box if pos, else -1.0)
//
// Bit-exact vs numpy f32: __f*_rn intrinsics (no FMA contraction), op order
// mirrors the jnp reference; argmax ties: first index (strict > scan).
//
// Round-8 structure: 2 anchors/thread written in ROUND-1's exact codegen
// style (the only shape that compiled clean: VGPR=20, no spill-write
// inflation). All-scalar loads/stores, 32-bit indices, scalar gb[g][j] LDS
// reads shared by both IoU chains, in-loop LDS u64 slot atomicMax gated
// iou>=0.3. Rounds 3-7 all spilled (WRITE_SIZE +8-10MB = per-thread spill
// writes); every one of them had float4 aggregate loads in the loop path --
// avoided entirely here. Second anchor at stride H=(N+1)/2 so both streams
// keep R1's 24B/lane coalescing.
// LDS-bound model: 15.3 waves/CU x 7 ds_read x 5.7cyc x 128 g ~= 33us.
//
// ws layout: [0,1024) slots[128] u64; [1024,1028) ticket counter.

#define MMAX 128

template <int MC>
__global__ __launch_bounds__(256) void iou_main(
    const float* __restrict__ bx, const float* __restrict__ gt,
    const int* __restrict__ gl,
    float* __restrict__ out_lab, float* __restrict__ out_bb,
    unsigned long long* __restrict__ slots, unsigned int* __restrict__ counter,
    int N, int Mrt, int nblocks)
{
    const int M = MC ? MC : Mrt;
    const int tid = threadIdx.x;

    // ---- stage gt boxes + area + label into LDS; zero LDS slots ----
    __shared__ float gb[MMAX][8];              // x0,y0,z0,x1,y1,z1,area,label
    __shared__ unsigned long long lsl[MMAX];   // per-block per-gt max slot
    if (tid < M) {
        const float* gp = gt + (size_t)tid * 6;
        float x0 = gp[0], y0 = gp[1], z0 = gp[2];
        float x1 = gp[3], y1 = gp[4], z1 = gp[5];
        float area = __fmul_rn(__fmul_rn(__fsub_rn(x1, x0), __fsub_rn(y1, y0)),
                               __fsub_rn(z1, z0));
        gb[tid][0] = x0; gb[tid][1] = y0; gb[tid][2] = z0; gb[tid][3] = x1;
        gb[tid][4] = y1; gb[tid][5] = z1; gb[tid][6] = area;
        gb[tid][7] = (float)gl[tid];
    }
    if (tid < MMAX) lsl[tid] = 0ULL;
    __syncthreads();

    // ---- two anchors per thread: a in [0,H), b = a + H (R1-style loads) ----
    const int H = (N + 1) >> 1;
    const int a = blockIdx.x * 256 + tid;
    const int b = a + H;
    const bool va = (a < H);          // a < H <= N
    const bool vb = va && (b < N);

    float ax0 = 0.f, ay0 = 0.f, az0 = 0.f, ax1 = 0.f, ay1 = 0.f, az1 = 0.f;
    if (va) {
        const float* p = bx + (size_t)a * 6;
        ax0 = p[0]; ay0 = p[1]; az0 = p[2];
        ax1 = p[3]; ay1 = p[4]; az1 = p[5];
    }
    float bx0 = 0.f, by0 = 0.f, bz0 = 0.f, bx1 = 0.f, by1 = 0.f, bz1 = 0.f;
    if (vb) {
        const float* p = bx + (size_t)b * 6;
        bx0 = p[0]; by0 = p[1]; bz0 = p[2];
        bx1 = p[3]; by1 = p[4]; bz1 = p[5];
    }

    const float a1a = __fmul_rn(__fmul_rn(__fsub_rn(ax1, ax0),
                       __fsub_rn(ay1, ay0)), __fsub_rn(az1, az0));
    const float a1b = __fmul_rn(__fmul_rn(__fsub_rn(bx1, bx0),
                       __fsub_rn(by1, by0)), __fsub_rn(bz1, bz0));

    // best=0: iou==0 never strict-beats it (matches jnp.argmax first-index,
    // all-zero row -> argmax 0).
    float bestA = 0.f, bestB = 0.f;
    int   argA = 0,    argB = 0;

    for (int g = 0; g < M; ++g) {
        // 7 scalar LDS reads, shared by both IoU chains (R1-proven pattern)
        const float gx0 = gb[g][0], gy0 = gb[g][1], gz0 = gb[g][2];
        const float gx1 = gb[g][3], gy1 = gb[g][4], gz1 = gb[g][5];
        const float ga  = gb[g][6];
        {
            float cx = fmaxf(__fsub_rn(fminf(ax1, gx1), fmaxf(ax0, gx0)), 0.f);
            float cy = fmaxf(__fsub_rn(fminf(ay1, gy1), fmaxf(ay0, gy0)), 0.f);
            float cz = fmaxf(__fsub_rn(fminf(az1, gz1), fmaxf(az0, gz0)), 0.f);
            float inter = __fmul_rn(__fmul_rn(cx, cy), cz);
            if (inter > 0.f) {                  // ~0.3% of pairs
                float den = __fadd_rn(__fsub_rn(__fadd_rn(a1a, ga), inter), 1e-7f);
                float iou = __fdiv_rn(inter, den);
                if (iou > bestA) { bestA = iou; argA = g; }
                if (iou >= 0.3f) {
                    // slot != 0 <=> column max >= MIN_POS_IOU; smallest-anchor
                    // tie-break via ~anchor in low bits.
                    unsigned long long enc =
                        ((unsigned long long)__float_as_uint(iou) << 32) |
                        (unsigned long long)(0xFFFFFFFFu - (unsigned)a);
                    atomicMax(&lsl[g], enc);
                }
            }
        }
        {
            float cx = fmaxf(__fsub_rn(fminf(bx1, gx1), fmaxf(bx0, gx0)), 0.f);
            float cy = fmaxf(__fsub_rn(fminf(by1, gy1), fmaxf(by0, gy0)), 0.f);
            float cz = fmaxf(__fsub_rn(fminf(bz1, gz1), fmaxf(bz0, gz0)), 0.f);
            float inter = __fmul_rn(__fmul_rn(cx, cy), cz);
            if (inter > 0.f) {
                float den = __fadd_rn(__fsub_rn(__fadd_rn(a1b, ga), inter), 1e-7f);
                float iou = __fdiv_rn(inter, den);
                if (iou > bestB) { bestB = iou; argB = g; }
                if (iou >= 0.3f) {
                    unsigned long long enc =
                        ((unsigned long long)__float_as_uint(iou) << 32) |
                        (unsigned long long)(0xFFFFFFFFu - (unsigned)b);
                    atomicMax(&lsl[g], enc);
                }
            }
        }
    }

    // ---- epilogue: labels + boxes, R1-style scalar writes ----
    if (va) {
        float lab;
        if (bestA >= 0.7f) lab = gb[argA][7];
        else               lab = (bestA < 0.3f) ? 0.f : -1.f;
        out_lab[a] = lab;
        float* ob = out_bb + (size_t)a * 6;
        if (bestA >= 0.7f) {
            ob[0] = gb[argA][0]; ob[1] = gb[argA][1]; ob[2] = gb[argA][2];
            ob[3] = gb[argA][3]; ob[4] = gb[argA][4]; ob[5] = gb[argA][5];
        } else {
            ob[0] = -1.f; ob[1] = -1.f; ob[2] = -1.f;
            ob[3] = -1.f; ob[4] = -1.f; ob[5] = -1.f;
        }
    }
    if (vb) {
        float lab;
        if (bestB >= 0.7f) lab = gb[argB][7];
        else               lab = (bestB < 0.3f) ? 0.f : -1.f;
        out_lab[b] = lab;
        float* ob = out_bb + (size_t)b * 6;
        if (bestB >= 0.7f) {
            ob[0] = gb[argB][0]; ob[1] = gb[argB][1]; ob[2] = gb[argB][2];
            ob[3] = gb[argB][3]; ob[4] = gb[argB][4]; ob[5] = gb[argB][5];
        } else {
            ob[0] = -1.f; ob[1] = -1.f; ob[2] = -1.f;
            ob[3] = -1.f; ob[4] = -1.f; ob[5] = -1.f;
        }
    }

    // ---- flush per-block per-gt maxima to global slots ----
    __syncthreads();
    for (int g = tid; g < M; g += 256) {
        unsigned long long v = lsl[g];
        if (v) atomicMax(&slots[g], v);
    }

    // ---- last-finished block applies the low-quality override ----
    __shared__ unsigned int s_ticket;
    __threadfence();                   // stores+atomics visible device-wide
    __syncthreads();
    if (tid == 0) s_ticket = atomicAdd(counter, 1u);
    __syncthreads();
    if (s_ticket != (unsigned)(nblocks - 1)) return;

    __shared__ int s_anchor[MMAX];
    __shared__ int s_cand[MMAX];
    int anchor = -1, cand = 0;
    if (tid < M) {
        unsigned long long v = atomicMax(&slots[tid], 0ULL);   // coherent read
        if (v != 0ULL) {               // gt_iou_max >= 0.3
            anchor = (int)(0xFFFFFFFFu - (unsigned)(v & 0xFFFFFFFFu));
            cand   = tid + 1;
        }
    }
    if (tid < MMAX) { s_anchor[tid] = anchor; s_cand[tid] = cand; }
    __syncthreads();
    if (tid < M && cand > 0) {
        // Largest gt index targeting the same anchor wins (.at[].max scatter).
        bool win = true;
        for (int j = 0; j < M; ++j)
            if (s_cand[j] > cand && s_anchor[j] == anchor) win = false;
        if (win) {
            out_lab[anchor] = gb[tid][7];
            float* ob = out_bb + (size_t)anchor * 6;
            ob[0] = gb[tid][0]; ob[1] = gb[tid][1]; ob[2] = gb[tid][2];
            ob[3] = gb[tid][3]; ob[4] = gb[tid][4]; ob[5] = gb[tid][5];
        }
    }
}

extern "C" void kernel_launch(void* const* d_in, const int* in_sizes, int n_in,
                              void* d_out, int out_size, void* d_ws, size_t ws_size,
                              hipStream_t stream)
{
    const float* bx = (const float*)d_in[0];
    const float* gt = (const float*)d_in[1];
    const int*   gl = (const int*)d_in[2];
    const int N = in_sizes[0] / 6;
    int M = in_sizes[1] / 6;
    if (M > MMAX) M = MMAX;

    float* out_lab = (float*)d_out;
    float* out_bb  = (float*)d_out + N;

    unsigned long long* slots = (unsigned long long*)d_ws;
    unsigned int* counter = (unsigned int*)((char*)d_ws + MMAX * 8);

    // counter + slots MUST be re-zeroed every call (ws is poisoned once, not
    // re-poisoned between timed replays).
    hipMemsetAsync(d_ws, 0, MMAX * 8 + 16, stream);

    const int H = (N + 1) / 2;
    const int nblocks = (H + 255) / 256;

    if (M == MMAX) {
        hipLaunchKernelGGL(iou_main<MMAX>, dim3(nblocks), dim3(256), 0, stream,
                           bx, gt, gl, out_lab, out_bb, slots, counter, N, M, nblocks);
    } else {
        hipLaunchKernelGGL(iou_main<0>, dim3(nblocks), dim3(256), 0, stream,
                           bx, gt, gl, out_lab, out_bb, slots, counter, N, M, nblocks);
    }
}

// Round 9
// 71.287 us; speedup vs baseline: 2.3238x; 2.2889x over previous
//
#include <hip/hip_runtime.h>

// IoU assigner: N anchors x M gts (3D, 6 coords). Outputs (concatenated, f32):
//   out[0:N]   labels (-1 ignore, 0 neg, gt_label pos)
//   out[N:7N]  assigned boxes (gt box if pos, else -1.0)
//
// Bit-exact vs numpy f32: __f*_rn intrinsics (no FMA contraction), op order
// mirrors the jnp reference; argmax ties: first index (strict > scan).
//
// Round-9 experiment: R8's loop body VERBATIM (2 anchors/thread at stride
// H=(N+1)/2, R1-style scalar loads, 7 shared ds_read_b32 per gt, in-loop LDS
// u64 slot atomicMax gated iou>=0.3) but with the FUSED OVERRIDE TAIL REMOVED
// -- override is a separate 1-block kernel (R0-proven). Every spilling round
// (R3-R8) had the fused ticket/override tail; the only clean kernel (R1,
// VGPR=20, no spill-write inflation) was unfused. This isolates fusion as
// the last untested spill trigger.
//
// ws layout: [0,1024) slots[128] u64.

#define MMAX 128

template <int MC>
__global__ __launch_bounds__(256) void iou_main(
    const float* __restrict__ bx, const float* __restrict__ gt,
    const int* __restrict__ gl,
    float* __restrict__ out_lab, float* __restrict__ out_bb,
    unsigned long long* __restrict__ slots,
    int N, int Mrt)
{
    const int M = MC ? MC : Mrt;
    const int tid = threadIdx.x;

    // ---- stage gt boxes + area + label into LDS; zero LDS slots ----
    __shared__ float gb[MMAX][8];              // x0,y0,z0,x1,y1,z1,area,label
    __shared__ unsigned long long lsl[MMAX];   // per-block per-gt max slot
    if (tid < M) {
        const float* gp = gt + (size_t)tid * 6;
        float x0 = gp[0], y0 = gp[1], z0 = gp[2];
        float x1 = gp[3], y1 = gp[4], z1 = gp[5];
        float area = __fmul_rn(__fmul_rn(__fsub_rn(x1, x0), __fsub_rn(y1, y0)),
                               __fsub_rn(z1, z0));
        gb[tid][0] = x0; gb[tid][1] = y0; gb[tid][2] = z0; gb[tid][3] = x1;
        gb[tid][4] = y1; gb[tid][5] = z1; gb[tid][6] = area;
        gb[tid][7] = (float)gl[tid];
    }
    if (tid < MMAX) lsl[tid] = 0ULL;
    __syncthreads();

    // ---- two anchors per thread: a in [0,H), b = a + H ----
    const int H = (N + 1) >> 1;
    const int a = blockIdx.x * 256 + tid;
    const int b = a + H;
    const bool va = (a < H);          // a < H <= N
    const bool vb = va && (b < N);

    float ax0 = 0.f, ay0 = 0.f, az0 = 0.f, ax1 = 0.f, ay1 = 0.f, az1 = 0.f;
    if (va) {
        const float* p = bx + (size_t)a * 6;
        ax0 = p[0]; ay0 = p[1]; az0 = p[2];
        ax1 = p[3]; ay1 = p[4]; az1 = p[5];
    }
    float bx0 = 0.f, by0 = 0.f, bz0 = 0.f, bx1 = 0.f, by1 = 0.f, bz1 = 0.f;
    if (vb) {
        const float* p = bx + (size_t)b * 6;
        bx0 = p[0]; by0 = p[1]; bz0 = p[2];
        bx1 = p[3]; by1 = p[4]; bz1 = p[5];
    }

    const float a1a = __fmul_rn(__fmul_rn(__fsub_rn(ax1, ax0),
                       __fsub_rn(ay1, ay0)), __fsub_rn(az1, az0));
    const float a1b = __fmul_rn(__fmul_rn(__fsub_rn(bx1, bx0),
                       __fsub_rn(by1, by0)), __fsub_rn(bz1, bz0));

    // best=0: iou==0 never strict-beats it (matches jnp.argmax first-index,
    // all-zero row -> argmax 0).
    float bestA = 0.f, bestB = 0.f;
    int   argA = 0,    argB = 0;

    for (int g = 0; g < M; ++g) {
        // 7 scalar LDS reads, shared by both IoU chains (R1-proven pattern)
        const float gx0 = gb[g][0], gy0 = gb[g][1], gz0 = gb[g][2];
        const float gx1 = gb[g][3], gy1 = gb[g][4], gz1 = gb[g][5];
        const float ga  = gb[g][6];
        {
            float cx = fmaxf(__fsub_rn(fminf(ax1, gx1), fmaxf(ax0, gx0)), 0.f);
            float cy = fmaxf(__fsub_rn(fminf(ay1, gy1), fmaxf(ay0, gy0)), 0.f);
            float cz = fmaxf(__fsub_rn(fminf(az1, gz1), fmaxf(az0, gz0)), 0.f);
            float inter = __fmul_rn(__fmul_rn(cx, cy), cz);
            if (inter > 0.f) {                  // ~0.3% of pairs
                float den = __fadd_rn(__fsub_rn(__fadd_rn(a1a, ga), inter), 1e-7f);
                float iou = __fdiv_rn(inter, den);
                if (iou > bestA) { bestA = iou; argA = g; }
                if (iou >= 0.3f) {
                    // slot != 0 <=> column max >= MIN_POS_IOU; smallest-anchor
                    // tie-break via ~anchor in low bits.
                    unsigned long long enc =
                        ((unsigned long long)__float_as_uint(iou) << 32) |
                        (unsigned long long)(0xFFFFFFFFu - (unsigned)a);
                    atomicMax(&lsl[g], enc);
                }
            }
        }
        {
            float cx = fmaxf(__fsub_rn(fminf(bx1, gx1), fmaxf(bx0, gx0)), 0.f);
            float cy = fmaxf(__fsub_rn(fminf(by1, gy1), fmaxf(by0, gy0)), 0.f);
            float cz = fmaxf(__fsub_rn(fminf(bz1, gz1), fmaxf(bz0, gz0)), 0.f);
            float inter = __fmul_rn(__fmul_rn(cx, cy), cz);
            if (inter > 0.f) {
                float den = __fadd_rn(__fsub_rn(__fadd_rn(a1b, ga), inter), 1e-7f);
                float iou = __fdiv_rn(inter, den);
                if (iou > bestB) { bestB = iou; argB = g; }
                if (iou >= 0.3f) {
                    unsigned long long enc =
                        ((unsigned long long)__float_as_uint(iou) << 32) |
                        (unsigned long long)(0xFFFFFFFFu - (unsigned)b);
                    atomicMax(&lsl[g], enc);
                }
            }
        }
    }

    // ---- epilogue: labels + boxes, R1-style scalar writes ----
    if (va) {
        float lab;
        if (bestA >= 0.7f) lab = gb[argA][7];
        else               lab = (bestA < 0.3f) ? 0.f : -1.f;
        out_lab[a] = lab;
        float* ob = out_bb + (size_t)a * 6;
        if (bestA >= 0.7f) {
            ob[0] = gb[argA][0]; ob[1] = gb[argA][1]; ob[2] = gb[argA][2];
            ob[3] = gb[argA][3]; ob[4] = gb[argA][4]; ob[5] = gb[argA][5];
        } else {
            ob[0] = -1.f; ob[1] = -1.f; ob[2] = -1.f;
            ob[3] = -1.f; ob[4] = -1.f; ob[5] = -1.f;
        }
    }
    if (vb) {
        float lab;
        if (bestB >= 0.7f) lab = gb[argB][7];
        else               lab = (bestB < 0.3f) ? 0.f : -1.f;
        out_lab[b] = lab;
        float* ob = out_bb + (size_t)b * 6;
        if (bestB >= 0.7f) {
            ob[0] = gb[argB][0]; ob[1] = gb[argB][1]; ob[2] = gb[argB][2];
            ob[3] = gb[argB][3]; ob[4] = gb[argB][4]; ob[5] = gb[argB][5];
        } else {
            ob[0] = -1.f; ob[1] = -1.f; ob[2] = -1.f;
            ob[3] = -1.f; ob[4] = -1.f; ob[5] = -1.f;
        }
    }

    // ---- flush per-block per-gt maxima to global slots ----
    __syncthreads();
    for (int g = tid; g < M; g += 256) {
        unsigned long long v = lsl[g];
        if (v) atomicMax(&slots[g], v);
    }
}

// Low-quality override (separate dispatch, R0-proven): for each gt with a
// nonzero slot (column max >= 0.3), its argmax anchor gets that gt; when
// several gts pick the same anchor the LARGEST gt index wins (mirrors the
// reference's .at[].max scatter).
__global__ __launch_bounds__(MMAX) void iou_override(
    const float* __restrict__ gt, const int* __restrict__ gl,
    const unsigned long long* __restrict__ slots,
    float* __restrict__ out_lab, float* __restrict__ out_bb, int M)
{
    __shared__ int s_anchor[MMAX];
    __shared__ int s_cand[MMAX];
    const int i = threadIdx.x;

    int anchor = -1, cand = 0;
    if (i < M) {
        unsigned long long v = slots[i];
        if (v != 0ULL) {               // gt_iou_max >= 0.3 (gated at insert)
            anchor = (int)(0xFFFFFFFFu - (unsigned)(v & 0xFFFFFFFFu));
            cand   = i + 1;
        }
    }
    s_anchor[i] = anchor;
    s_cand[i]   = cand;
    __syncthreads();

    if (cand > 0) {
        bool win = true;
        for (int j = 0; j < M; ++j)
            if (s_cand[j] > cand && s_anchor[j] == anchor) { win = false; break; }
        if (win) {
            out_lab[anchor] = (float)gl[i];
            float* ob = out_bb + (size_t)anchor * 6;
            const float* gp = gt + (size_t)i * 6;
            ob[0] = gp[0]; ob[1] = gp[1]; ob[2] = gp[2];
            ob[3] = gp[3]; ob[4] = gp[4]; ob[5] = gp[5];
        }
    }
}

extern "C" void kernel_launch(void* const* d_in, const int* in_sizes, int n_in,
                              void* d_out, int out_size, void* d_ws, size_t ws_size,
                              hipStream_t stream)
{
    const float* bx = (const float*)d_in[0];
    const float* gt = (const float*)d_in[1];
    const int*   gl = (const int*)d_in[2];
    const int N = in_sizes[0] / 6;
    int M = in_sizes[1] / 6;
    if (M > MMAX) M = MMAX;

    float* out_lab = (float*)d_out;
    float* out_bb  = (float*)d_out + N;

    unsigned long long* slots = (unsigned long long*)d_ws;

    // slots MUST be re-zeroed every call (ws is poisoned once, not re-poisoned
    // between timed replays).
    hipMemsetAsync(d_ws, 0, MMAX * 8, stream);

    const int H = (N + 1) / 2;
    const int nblocks = (H + 255) / 256;

    if (M == MMAX) {
        hipLaunchKernelGGL(iou_main<MMAX>, dim3(nblocks), dim3(256), 0, stream,
                           bx, gt, gl, out_lab, out_bb, slots, N, M);
    } else {
        hipLaunchKernelGGL(iou_main<0>, dim3(nblocks), dim3(256), 0, stream,
                           bx, gt, gl, out_lab, out_bb, slots, N, M);
    }
    hipLaunchKernelGGL(iou_override, dim3(1), dim3(MMAX), 0, stream,
                       gt, gl, slots, out_lab, out_bb, M);
}